// Round 3
// baseline (48.499 us; speedup 1.0000x reference)
//
#include <hip/hip_runtime.h>
#include <math.h>

// Problem constants
#define BB 4096      // batch
#define DD 512       // feature dim
#define CC 1000      // num classes

typedef __attribute__((ext_vector_type(8))) short short8;
typedef __attribute__((ext_vector_type(4))) float f32x4;

// ---------------- ws layout (float slots) ----------------
#define OFF_ABF  0              // 4096x512 bf16 = 1048576 float slots
#define OFF_EBF  1048576        // 1024x512 bf16 = 262144
#define OFF_ESQ  1310720        // 1024
#define OFF_ASQ  1311744        // 4096
#define OFF_DREF 1315840        // 4096
#define OFF_PMIN 1319936        // 4096
#define OFF_CEP  1324032        // 3072
#define OFF_TRP  1327104        // 1024

__device__ __forceinline__ unsigned short f2bf(float x) {
    unsigned u = __float_as_uint(x);
    unsigned r = (u + 0x7FFFu + ((u >> 16) & 1u)) >> 16;   // RNE
    return (unsigned short)r;
}

// ---------------------------------------------------------------------------
// prep: blocks [0,1024): triplet + asq + exact fp32 dref + anchor->bf16 + pmin=INF
//       blocks [1024,1280): exemplar->bf16 (padded) + esq
// ---------------------------------------------------------------------------
__global__ __launch_bounds__(256) void prep_kernel(
    const float* __restrict__ a, const float* __restrict__ p,
    const float* __restrict__ n, const float* __restrict__ ex,
    const int* __restrict__ la,
    unsigned short* __restrict__ Abf, unsigned short* __restrict__ Ebf,
    float* __restrict__ esq, float* __restrict__ asq,
    float* __restrict__ dref, float* __restrict__ tr_part,
    float* __restrict__ pmin)
{
    const int bid = blockIdx.x;
    const int wid = threadIdx.x >> 6, lane = threadIdx.x & 63;
    if (bid < 1024) {
        // -------- triplet role: one wave per anchor row --------
        const int i = bid * 4 + wid;
        const int label = la[i];
        const float4* ar = (const float4*)(a + (size_t)i * DD);
        const float4* pr = (const float4*)(p + (size_t)i * DD);
        const float4* nr = (const float4*)(n + (size_t)i * DD);
        const float4* er = (const float4*)(ex + (size_t)label * DD);
        float sa = 0.f, sp = 0.f, sn = 0.f, se = 0.f;
#pragma unroll
        for (int k = 0; k < 2; k++) {
            const int j = lane + k * 64;
            float4 av = ar[j], pv = pr[j], nv = nr[j], ev = er[j];
            union { unsigned short u[4]; uint2 q; } o;
            o.u[0]=f2bf(av.x); o.u[1]=f2bf(av.y); o.u[2]=f2bf(av.z); o.u[3]=f2bf(av.w);
            *(uint2*)(Abf + (size_t)i * DD + j * 4) = o.q;
            sa += av.x*av.x + av.y*av.y + av.z*av.z + av.w*av.w;
            float dx = av.x-pv.x, dy = av.y-pv.y, dz = av.z-pv.z, dw = av.w-pv.w;
            sp += dx*dx + dy*dy + dz*dz + dw*dw;
            dx = av.x-nv.x; dy = av.y-nv.y; dz = av.z-nv.z; dw = av.w-nv.w;
            sn += dx*dx + dy*dy + dz*dz + dw*dw;
            dx = av.x-ev.x; dy = av.y-ev.y; dz = av.z-ev.z; dw = av.w-ev.w;
            se += dx*dx + dy*dy + dz*dz + dw*dw;
        }
        for (int off = 32; off; off >>= 1) {
            sa += __shfl_xor(sa, off);
            sp += __shfl_xor(sp, off);
            sn += __shfl_xor(sn, off);
            se += __shfl_xor(se, off);
        }
        __shared__ float ts[4];
        if (lane == 0) {
            asq[i]  = sa;
            dref[i] = sqrtf(se);
            pmin[i] = INFINITY;
            ts[wid] = fmaxf(sqrtf(sp) - sqrtf(sn), 0.f);
        }
        __syncthreads();
        if (threadIdx.x == 0) tr_part[bid] = ts[0] + ts[1] + ts[2] + ts[3];
    } else {
        // -------- exemplar role: one wave per (padded) class row --------
        const int c = (bid - 1024) * 4 + wid;   // [0,1024)
        float s = 0.f;
        if (c < CC) {
            const float4* row = (const float4*)(ex + (size_t)c * DD);
#pragma unroll
            for (int k = 0; k < 2; k++) {
                const int j = lane + k * 64;
                float4 v = row[j];
                union { unsigned short u[4]; uint2 q; } o;
                o.u[0]=f2bf(v.x); o.u[1]=f2bf(v.y); o.u[2]=f2bf(v.z); o.u[3]=f2bf(v.w);
                *(uint2*)(Ebf + (size_t)c * DD + j * 4) = o.q;
                s += v.x*v.x + v.y*v.y + v.z*v.z + v.w*v.w;
            }
            for (int off = 32; off; off >>= 1) s += __shfl_xor(s, off);
        } else {
            const uint2 z = make_uint2(0, 0);
#pragma unroll
            for (int k = 0; k < 2; k++) {
                const int j = lane + k * 64;
                *(uint2*)(Ebf + (size_t)c * DD + j * 4) = z;
            }
        }
        if (lane == 0) esq[c] = s;
    }
}

// ---------------------------------------------------------------------------
// main: role-split grid of 4096 blocks.
//   bid&3==0  -> GEMM+min block gb = bid>>2 in [0,1024)
//   else      -> CE block cb = bid - (bid>>2) - 1 in [0,3072)
// ---------------------------------------------------------------------------
#define GL2LDS(gsrc, ldst) __builtin_amdgcn_global_load_lds( \
    (const __attribute__((address_space(1))) unsigned int*)(gsrc), \
    (__attribute__((address_space(3))) unsigned int*)(ldst), 16, 0, 0)

__global__ __launch_bounds__(256) void main_kernel(
    const unsigned short* __restrict__ Ab, const unsigned short* __restrict__ Eb,
    const float* __restrict__ asq, const float* __restrict__ esq,
    const float* __restrict__ outp,
    const int* __restrict__ la, const int* __restrict__ ln,
    float* __restrict__ pmin, float* __restrict__ ce_part)
{
    __shared__ unsigned short lA[64 * 64];
    __shared__ unsigned short lB[64 * 64];
    __shared__ float s_pm[2][64];
    __shared__ float ps[4];

    const int bid = blockIdx.x;
    const int tid = threadIdx.x;
    const int w = tid >> 6, lane = tid & 63;

    if ((bid & 3) == 0) {
        // =================== GEMM + fused distance/min ===================
        const int gb = bid >> 2;
        const int wm = w >> 1, wn = w & 1;
        const int hi = lane >> 4, lo = lane & 15;
        const int lrow = lane >> 3, l8 = lane & 7;
        const int gm0 = (gb >> 4) * 64, gn0 = (gb & 15) * 64;

        f32x4 acc[2][2];
#pragma unroll
        for (int mi = 0; mi < 2; mi++)
#pragma unroll
            for (int ni = 0; ni < 2; ni++) acc[mi][ni] = (f32x4){0.f, 0.f, 0.f, 0.f};

        for (int kt = 0; kt < DD / 64; kt++) {
#pragma unroll
            for (int i = 0; i < 2; i++) {
                int r0 = w * 16 + i * 8;
                int row = r0 + lrow;
                int c16 = l8 ^ (row & 7);
                GL2LDS(Ab + ((size_t)(gm0 + row) << 9) + kt * 64 + (c16 << 3), &lA[r0 * 64]);
                GL2LDS(Eb + ((size_t)(gn0 + row) << 9) + kt * 64 + (c16 << 3), &lB[r0 * 64]);
            }
            asm volatile("s_waitcnt vmcnt(0)" ::: "memory");
            __syncthreads();

#pragma unroll
            for (int kk = 0; kk < 2; kk++) {
                int g16 = kk * 4 + hi;
                int rA0 = wm * 32 + lo,      rA1 = wm * 32 + 16 + lo;
                int rB0 = wn * 32 + lo,      rB1 = wn * 32 + 16 + lo;
                short8 a0 = *(const short8*)&lA[rA0 * 64 + ((g16 ^ (rA0 & 7)) << 3)];
                short8 a1 = *(const short8*)&lA[rA1 * 64 + ((g16 ^ (rA1 & 7)) << 3)];
                short8 b0 = *(const short8*)&lB[rB0 * 64 + ((g16 ^ (rB0 & 7)) << 3)];
                short8 b1 = *(const short8*)&lB[rB1 * 64 + ((g16 ^ (rB1 & 7)) << 3)];
                acc[0][0] = __builtin_amdgcn_mfma_f32_16x16x32_bf16(a0, b0, acc[0][0], 0, 0, 0);
                acc[0][1] = __builtin_amdgcn_mfma_f32_16x16x32_bf16(a0, b1, acc[0][1], 0, 0, 0);
                acc[1][0] = __builtin_amdgcn_mfma_f32_16x16x32_bf16(a1, b0, acc[1][0], 0, 0, 0);
                acc[1][1] = __builtin_amdgcn_mfma_f32_16x16x32_bf16(a1, b1, acc[1][1], 0, 0, 0);
            }
            __syncthreads();
        }

        // epilogue: d = sqrt(asq + esq - 2 dot); per-block col-min; atomicMin
        float aq[2][4];
        {
            float4 a0 = *(const float4*)&asq[gm0 + wm * 32 + hi * 4];
            float4 a1 = *(const float4*)&asq[gm0 + wm * 32 + 16 + hi * 4];
            aq[0][0]=a0.x; aq[0][1]=a0.y; aq[0][2]=a0.z; aq[0][3]=a0.w;
            aq[1][0]=a1.x; aq[1][1]=a1.y; aq[1][2]=a1.z; aq[1][3]=a1.w;
        }
        float esqc[2]; int bad[2];
#pragma unroll
        for (int ni = 0; ni < 2; ni++) {
            int gn = gn0 + wn * 32 + ni * 16 + lo;
            esqc[ni] = esq[gn];
            bad[ni] = (gn >= CC);
        }
        float vmin[2][4];
#pragma unroll
        for (int mi = 0; mi < 2; mi++)
#pragma unroll
            for (int j = 0; j < 4; j++) {
                float best = INFINITY;
#pragma unroll
                for (int ni = 0; ni < 2; ni++) {
                    float d2 = aq[mi][j] + esqc[ni] - 2.f * acc[mi][ni][j];
                    float d = sqrtf(fmaxf(d2, 0.f));
                    if (bad[ni]) d = INFINITY;
                    best = fminf(best, d);
                }
                vmin[mi][j] = best;
            }
#pragma unroll
        for (int off = 1; off < 16; off <<= 1)
#pragma unroll
            for (int mi = 0; mi < 2; mi++)
#pragma unroll
                for (int j = 0; j < 4; j++)
                    vmin[mi][j] = fminf(vmin[mi][j], __shfl_xor(vmin[mi][j], off));

        if (lo == 0) {
#pragma unroll
            for (int mi = 0; mi < 2; mi++)
#pragma unroll
                for (int j = 0; j < 4; j++)
                    s_pm[wn][wm * 32 + mi * 16 + hi * 4 + j] = vmin[mi][j];
        }
        __syncthreads();
        if (tid < 64) {
            float m2 = fminf(s_pm[0][tid], s_pm[1][tid]);
            // d >= 0 -> float order == int order; min is order-independent.
            atomicMin((int*)pmin + gm0 + tid, __float_as_int(m2));
        }
    } else {
        // =================== CE: one wave per row ===================
        const int cb = bid - (bid >> 2) - 1;    // [0,3072)
        const int r = cb * 4 + w;               // [0,12288)
        const int label = (r < 2 * BB) ? la[r & (BB - 1)] : ln[r - 2 * BB];
        const float* row = outp + (size_t)r * CC;
        float v[16];
#pragma unroll
        for (int k = 0; k < 16; k++) {
            int j = lane + k * 64;
            v[k] = (j < CC) ? row[j] : -INFINITY;
        }
        float m = v[0];
#pragma unroll
        for (int k = 1; k < 16; k++) m = fmaxf(m, v[k]);
        for (int off = 32; off; off >>= 1) m = fmaxf(m, __shfl_xor(m, off));
        float s = 0.f, lv = 0.f;
#pragma unroll
        for (int k = 0; k < 16; k++) {
            int j = lane + k * 64;
            s += __expf(v[k] - m);
            lv += (j == label) ? v[k] : 0.f;
        }
        for (int off = 32; off; off >>= 1) {
            s += __shfl_xor(s, off);
            lv += __shfl_xor(lv, off);
        }
        if (lane == 0) ps[w] = -(lv - m - __logf(s));
        __syncthreads();
        if (tid == 0) ce_part[cb] = ps[0] + ps[1] + ps[2] + ps[3];
    }
}

// ---------------------------------------------------------------------------
// final: reduce partials; center loss from pmin + dref; combine.
// ---------------------------------------------------------------------------
__global__ __launch_bounds__(1024) void final_kernel(
    const float* __restrict__ ce_part, const float* __restrict__ tr_part,
    const float* __restrict__ pmin, const float* __restrict__ dref,
    float* __restrict__ out)
{
    int tid = threadIdx.x;
    float ce = 0.f, tr = tr_part[tid], ctr = 0.f;
#pragma unroll
    for (int j = 0; j < 3; j++) ce += ce_part[tid + j * 1024];
#pragma unroll
    for (int a = 0; a < 4; a++) {
        int m = a * 1024 + tid;
        ctr += fmaxf(dref[m] - pmin[m], 0.f);
    }
    for (int off = 32; off; off >>= 1) {
        ce += __shfl_xor(ce, off);
        tr += __shfl_xor(tr, off);
        ctr += __shfl_xor(ctr, off);
    }
    __shared__ float s[3][16];
    int wid = tid >> 6, lane = tid & 63;
    if (lane == 0) { s[0][wid] = ce; s[1][wid] = tr; s[2][wid] = ctr; }
    __syncthreads();
    if (tid == 0) {
        float tce = 0.f, ttr = 0.f, tctr = 0.f;
#pragma unroll
        for (int w = 0; w < 16; w++) { tce += s[0][w]; ttr += s[1][w]; tctr += s[2][w]; }
        float lsm = tce / (3.f * BB);
        out[0] = lsm + 0.1f * tctr + 1.0f * ttr;
        out[1] = ttr;
        out[2] = lsm;
        out[3] = tctr;
    }
}

extern "C" void kernel_launch(void* const* d_in, const int* in_sizes, int n_in,
                              void* d_out, int out_size, void* d_ws, size_t ws_size,
                              hipStream_t stream) {
    const float* anchor   = (const float*)d_in[0];
    const float* positive = (const float*)d_in[1];
    const float* negative = (const float*)d_in[2];
    const float* outputs  = (const float*)d_in[3];
    const int*   la       = (const int*)d_in[4];
    const int*   ln       = (const int*)d_in[5];
    const float* ex       = (const float*)d_in[6];
    float* out = (float*)d_out;
    float* ws  = (float*)d_ws;

    unsigned short* Abf = (unsigned short*)(ws + OFF_ABF);
    unsigned short* Ebf = (unsigned short*)(ws + OFF_EBF);
    float* esq      = ws + OFF_ESQ;
    float* asq      = ws + OFF_ASQ;
    float* dref     = ws + OFF_DREF;
    float* pmin     = ws + OFF_PMIN;
    float* ce_part  = ws + OFF_CEP;
    float* tr_part  = ws + OFF_TRP;

    hipLaunchKernelGGL(prep_kernel,  dim3(1280), dim3(256),  0, stream,
                       anchor, positive, negative, ex, la, Abf, Ebf, esq, asq, dref, tr_part, pmin);
    hipLaunchKernelGGL(main_kernel,  dim3(4096), dim3(256),  0, stream,
                       Abf, Ebf, asq, esq, outputs, la, ln, pmin, ce_part);
    hipLaunchKernelGGL(final_kernel, dim3(1),    dim3(1024), 0, stream,
                       ce_part, tr_part, pmin, dref, out);
}

// Round 4
// 47.364 us; speedup vs baseline: 1.0240x; 1.0240x over previous
//
#include <hip/hip_runtime.h>
#include <math.h>

// Problem constants
#define BB 4096      // batch
#define DD 512       // feature dim
#define CC 1000      // num classes

typedef __attribute__((ext_vector_type(8))) short short8;
typedef __attribute__((ext_vector_type(4))) float f32x4;

// ---------------- ws layout (float slots) ----------------
#define OFF_ABF  0              // 4096x512 bf16 = 1048576 float slots
#define OFF_EBF  1048576        // 1024x512 bf16 = 262144
#define OFF_ESQ  1310720        // 1024
#define OFF_ASQ  1311744        // 4096
#define OFF_DREF 1315840        // 4096
#define OFF_PMIN 1319936        // 4096
#define OFF_CEP  1324032        // 3072
#define OFF_TRP  1327104        // 1024

__device__ __forceinline__ unsigned short f2bf(float x) {
    unsigned u = __float_as_uint(x);
    unsigned r = (u + 0x7FFFu + ((u >> 16) & 1u)) >> 16;   // RNE
    return (unsigned short)r;
}

// ---------------------------------------------------------------------------
// prep: blocks [0,1024): triplet + asq + exact fp32 dref + anchor->bf16 + pmin=INF
//       blocks [1024,1280): exemplar->bf16 (padded) + esq
// ---------------------------------------------------------------------------
__global__ __launch_bounds__(256) void prep_kernel(
    const float* __restrict__ a, const float* __restrict__ p,
    const float* __restrict__ n, const float* __restrict__ ex,
    const int* __restrict__ la,
    unsigned short* __restrict__ Abf, unsigned short* __restrict__ Ebf,
    float* __restrict__ esq, float* __restrict__ asq,
    float* __restrict__ dref, float* __restrict__ tr_part,
    float* __restrict__ pmin)
{
    const int bid = blockIdx.x;
    const int wid = threadIdx.x >> 6, lane = threadIdx.x & 63;
    if (bid < 1024) {
        // -------- triplet role: one wave per anchor row --------
        const int i = bid * 4 + wid;
        const int label = la[i];
        const float4* ar = (const float4*)(a + (size_t)i * DD);
        const float4* pr = (const float4*)(p + (size_t)i * DD);
        const float4* nr = (const float4*)(n + (size_t)i * DD);
        const float4* er = (const float4*)(ex + (size_t)label * DD);
        float sa = 0.f, sp = 0.f, sn = 0.f, se = 0.f;
#pragma unroll
        for (int k = 0; k < 2; k++) {
            const int j = lane + k * 64;
            float4 av = ar[j], pv = pr[j], nv = nr[j], ev = er[j];
            union { unsigned short u[4]; uint2 q; } o;
            o.u[0]=f2bf(av.x); o.u[1]=f2bf(av.y); o.u[2]=f2bf(av.z); o.u[3]=f2bf(av.w);
            *(uint2*)(Abf + (size_t)i * DD + j * 4) = o.q;
            sa += av.x*av.x + av.y*av.y + av.z*av.z + av.w*av.w;
            float dx = av.x-pv.x, dy = av.y-pv.y, dz = av.z-pv.z, dw = av.w-pv.w;
            sp += dx*dx + dy*dy + dz*dz + dw*dw;
            dx = av.x-nv.x; dy = av.y-nv.y; dz = av.z-nv.z; dw = av.w-nv.w;
            sn += dx*dx + dy*dy + dz*dz + dw*dw;
            dx = av.x-ev.x; dy = av.y-ev.y; dz = av.z-ev.z; dw = av.w-ev.w;
            se += dx*dx + dy*dy + dz*dz + dw*dw;
        }
        for (int off = 32; off; off >>= 1) {
            sa += __shfl_xor(sa, off);
            sp += __shfl_xor(sp, off);
            sn += __shfl_xor(sn, off);
            se += __shfl_xor(se, off);
        }
        __shared__ float ts[4];
        if (lane == 0) {
            asq[i]  = sa;
            dref[i] = sqrtf(se);
            pmin[i] = INFINITY;
            ts[wid] = fmaxf(sqrtf(sp) - sqrtf(sn), 0.f);
        }
        __syncthreads();
        if (threadIdx.x == 0) tr_part[bid] = ts[0] + ts[1] + ts[2] + ts[3];
    } else {
        // -------- exemplar role: one wave per (padded) class row --------
        const int c = (bid - 1024) * 4 + wid;   // [0,1024)
        float s = 0.f;
        if (c < CC) {
            const float4* row = (const float4*)(ex + (size_t)c * DD);
#pragma unroll
            for (int k = 0; k < 2; k++) {
                const int j = lane + k * 64;
                float4 v = row[j];
                union { unsigned short u[4]; uint2 q; } o;
                o.u[0]=f2bf(v.x); o.u[1]=f2bf(v.y); o.u[2]=f2bf(v.z); o.u[3]=f2bf(v.w);
                *(uint2*)(Ebf + (size_t)c * DD + j * 4) = o.q;
                s += v.x*v.x + v.y*v.y + v.z*v.z + v.w*v.w;
            }
            for (int off = 32; off; off >>= 1) s += __shfl_xor(s, off);
        } else {
            const uint2 z = make_uint2(0, 0);
#pragma unroll
            for (int k = 0; k < 2; k++) {
                const int j = lane + k * 64;
                *(uint2*)(Ebf + (size_t)c * DD + j * 4) = z;
            }
        }
        if (lane == 0) esq[c] = s;
    }
}

// ---------------------------------------------------------------------------
// main: role-split grid of 4096 blocks, XCD-uniform role assignment.
// chunk = bid>>3 (8 consecutive blocks span all 8 XCDs).
//   chunk%4==0 -> GEMM block gb = (chunk>>2)*8 + (bid&7)   in [0,1024)
//   else       -> CE block  cb = (chunk - (chunk>>2) - 1)*8 + (bid&7) in [0,3072)
// ---------------------------------------------------------------------------
#define GL2LDS(gsrc, ldst) __builtin_amdgcn_global_load_lds( \
    (const __attribute__((address_space(1))) unsigned int*)(gsrc), \
    (__attribute__((address_space(3))) unsigned int*)(ldst), 16, 0, 0)

__global__ __launch_bounds__(256) void main_kernel(
    const unsigned short* __restrict__ Ab, const unsigned short* __restrict__ Eb,
    const float* __restrict__ asq, const float* __restrict__ esq,
    const float* __restrict__ outp,
    const int* __restrict__ la, const int* __restrict__ ln,
    float* __restrict__ pmin, float* __restrict__ ce_part)
{
    __shared__ unsigned short lA[64 * 64];
    __shared__ unsigned short lB[64 * 64];
    __shared__ float s_pm[2][64];
    __shared__ float ps[4];

    const int bid = blockIdx.x;
    const int tid = threadIdx.x;
    const int w = tid >> 6, lane = tid & 63;
    const int chunk = bid >> 3, sub = bid & 7;

    if ((chunk & 3) == 0) {
        // =================== GEMM + fused distance/min ===================
        const int gb = (chunk >> 2) * 8 + sub;          // [0,1024)
        const int wm = w >> 1, wn = w & 1;
        const int hi = lane >> 4, lo = lane & 15;
        const int lrow = lane >> 3, l8 = lane & 7;
        const int gm0 = (gb >> 4) * 64, gn0 = (gb & 15) * 64;

        f32x4 acc[2][2];
#pragma unroll
        for (int mi = 0; mi < 2; mi++)
#pragma unroll
            for (int ni = 0; ni < 2; ni++) acc[mi][ni] = (f32x4){0.f, 0.f, 0.f, 0.f};

        for (int kt = 0; kt < DD / 64; kt++) {
#pragma unroll
            for (int i = 0; i < 2; i++) {
                int r0 = w * 16 + i * 8;
                int row = r0 + lrow;
                int c16 = l8 ^ (row & 7);
                GL2LDS(Ab + ((size_t)(gm0 + row) << 9) + kt * 64 + (c16 << 3), &lA[r0 * 64]);
                GL2LDS(Eb + ((size_t)(gn0 + row) << 9) + kt * 64 + (c16 << 3), &lB[r0 * 64]);
            }
            asm volatile("s_waitcnt vmcnt(0)" ::: "memory");
            __syncthreads();

#pragma unroll
            for (int kk = 0; kk < 2; kk++) {
                int g16 = kk * 4 + hi;
                int rA0 = wm * 32 + lo,      rA1 = wm * 32 + 16 + lo;
                int rB0 = wn * 32 + lo,      rB1 = wn * 32 + 16 + lo;
                short8 a0 = *(const short8*)&lA[rA0 * 64 + ((g16 ^ (rA0 & 7)) << 3)];
                short8 a1 = *(const short8*)&lA[rA1 * 64 + ((g16 ^ (rA1 & 7)) << 3)];
                short8 b0 = *(const short8*)&lB[rB0 * 64 + ((g16 ^ (rB0 & 7)) << 3)];
                short8 b1 = *(const short8*)&lB[rB1 * 64 + ((g16 ^ (rB1 & 7)) << 3)];
                acc[0][0] = __builtin_amdgcn_mfma_f32_16x16x32_bf16(a0, b0, acc[0][0], 0, 0, 0);
                acc[0][1] = __builtin_amdgcn_mfma_f32_16x16x32_bf16(a0, b1, acc[0][1], 0, 0, 0);
                acc[1][0] = __builtin_amdgcn_mfma_f32_16x16x32_bf16(a1, b0, acc[1][0], 0, 0, 0);
                acc[1][1] = __builtin_amdgcn_mfma_f32_16x16x32_bf16(a1, b1, acc[1][1], 0, 0, 0);
            }
            __syncthreads();
        }

        // epilogue: d = sqrt(asq + esq - 2 dot); per-block col-min; atomicMin
        float aq[2][4];
        {
            float4 a0 = *(const float4*)&asq[gm0 + wm * 32 + hi * 4];
            float4 a1 = *(const float4*)&asq[gm0 + wm * 32 + 16 + hi * 4];
            aq[0][0]=a0.x; aq[0][1]=a0.y; aq[0][2]=a0.z; aq[0][3]=a0.w;
            aq[1][0]=a1.x; aq[1][1]=a1.y; aq[1][2]=a1.z; aq[1][3]=a1.w;
        }
        float esqc[2]; int bad[2];
#pragma unroll
        for (int ni = 0; ni < 2; ni++) {
            int gn = gn0 + wn * 32 + ni * 16 + lo;
            esqc[ni] = esq[gn];
            bad[ni] = (gn >= CC);
        }
        float vmin[2][4];
#pragma unroll
        for (int mi = 0; mi < 2; mi++)
#pragma unroll
            for (int j = 0; j < 4; j++) {
                float best = INFINITY;
#pragma unroll
                for (int ni = 0; ni < 2; ni++) {
                    float d2 = aq[mi][j] + esqc[ni] - 2.f * acc[mi][ni][j];
                    float d = sqrtf(fmaxf(d2, 0.f));
                    if (bad[ni]) d = INFINITY;
                    best = fminf(best, d);
                }
                vmin[mi][j] = best;
            }
#pragma unroll
        for (int off = 1; off < 16; off <<= 1)
#pragma unroll
            for (int mi = 0; mi < 2; mi++)
#pragma unroll
                for (int j = 0; j < 4; j++)
                    vmin[mi][j] = fminf(vmin[mi][j], __shfl_xor(vmin[mi][j], off));

        if (lo == 0) {
#pragma unroll
            for (int mi = 0; mi < 2; mi++)
#pragma unroll
                for (int j = 0; j < 4; j++)
                    s_pm[wn][wm * 32 + mi * 16 + hi * 4 + j] = vmin[mi][j];
        }
        __syncthreads();
        if (tid < 64) {
            float m2 = fminf(s_pm[0][tid], s_pm[1][tid]);
            // d >= 0 -> float order == int order; min is order-independent.
            atomicMin((int*)pmin + gm0 + tid, __float_as_int(m2));
        }
    } else {
        // =================== CE: one wave per row, float4 loads ===================
        const int cb = (chunk - (chunk >> 2) - 1) * 8 + sub;    // [0,3072)
        const int r = cb * 4 + w;                               // [0,12288)
        const int label = (r < 2 * BB) ? la[r & (BB - 1)] : ln[r - 2 * BB];
        const float4* row4 = (const float4*)(outp + (size_t)r * CC);   // 250 float4, 16B-aligned
        float4 v[4];
#pragma unroll
        for (int k = 0; k < 4; k++) {
            int j4 = lane + k * 64;
            v[k] = (j4 < 250) ? row4[j4]
                              : make_float4(-INFINITY, -INFINITY, -INFINITY, -INFINITY);
        }
        float m = -INFINITY;
#pragma unroll
        for (int k = 0; k < 4; k++)
            m = fmaxf(m, fmaxf(fmaxf(v[k].x, v[k].y), fmaxf(v[k].z, v[k].w)));
        for (int off = 32; off; off >>= 1) m = fmaxf(m, __shfl_xor(m, off));

        const int lj4 = label >> 2, lc = label & 3;
        float s = 0.f, lv = 0.f;
#pragma unroll
        for (int k = 0; k < 4; k++) {
            int j4 = lane + k * 64;
            s += __expf(v[k].x - m) + __expf(v[k].y - m)
               + __expf(v[k].z - m) + __expf(v[k].w - m);
            float comp = (lc == 0) ? v[k].x : (lc == 1) ? v[k].y : (lc == 2) ? v[k].z : v[k].w;
            lv += (j4 == lj4) ? comp : 0.f;
        }
        for (int off = 32; off; off >>= 1) {
            s += __shfl_xor(s, off);
            lv += __shfl_xor(lv, off);
        }
        if (lane == 0) ps[w] = -(lv - m - __logf(s));
        __syncthreads();
        if (tid == 0) ce_part[cb] = ps[0] + ps[1] + ps[2] + ps[3];
    }
}

// ---------------------------------------------------------------------------
// final: reduce partials; center loss from pmin + dref; combine.
// ---------------------------------------------------------------------------
__global__ __launch_bounds__(1024) void final_kernel(
    const float* __restrict__ ce_part, const float* __restrict__ tr_part,
    const float* __restrict__ pmin, const float* __restrict__ dref,
    float* __restrict__ out)
{
    int tid = threadIdx.x;
    float ce = 0.f, tr = tr_part[tid], ctr = 0.f;
#pragma unroll
    for (int j = 0; j < 3; j++) ce += ce_part[tid + j * 1024];
#pragma unroll
    for (int a = 0; a < 4; a++) {
        int m = a * 1024 + tid;
        ctr += fmaxf(dref[m] - pmin[m], 0.f);
    }
    for (int off = 32; off; off >>= 1) {
        ce += __shfl_xor(ce, off);
        tr += __shfl_xor(tr, off);
        ctr += __shfl_xor(ctr, off);
    }
    __shared__ float s[3][16];
    int wid = tid >> 6, lane = tid & 63;
    if (lane == 0) { s[0][wid] = ce; s[1][wid] = tr; s[2][wid] = ctr; }
    __syncthreads();
    if (tid == 0) {
        float tce = 0.f, ttr = 0.f, tctr = 0.f;
#pragma unroll
        for (int w = 0; w < 16; w++) { tce += s[0][w]; ttr += s[1][w]; tctr += s[2][w]; }
        float lsm = tce / (3.f * BB);
        out[0] = lsm + 0.1f * tctr + 1.0f * ttr;
        out[1] = ttr;
        out[2] = lsm;
        out[3] = tctr;
    }
}

extern "C" void kernel_launch(void* const* d_in, const int* in_sizes, int n_in,
                              void* d_out, int out_size, void* d_ws, size_t ws_size,
                              hipStream_t stream) {
    const float* anchor   = (const float*)d_in[0];
    const float* positive = (const float*)d_in[1];
    const float* negative = (const float*)d_in[2];
    const float* outputs  = (const float*)d_in[3];
    const int*   la       = (const int*)d_in[4];
    const int*   ln       = (const int*)d_in[5];
    const float* ex       = (const float*)d_in[6];
    float* out = (float*)d_out;
    float* ws  = (float*)d_ws;

    unsigned short* Abf = (unsigned short*)(ws + OFF_ABF);
    unsigned short* Ebf = (unsigned short*)(ws + OFF_EBF);
    float* esq      = ws + OFF_ESQ;
    float* asq      = ws + OFF_ASQ;
    float* dref     = ws + OFF_DREF;
    float* pmin     = ws + OFF_PMIN;
    float* ce_part  = ws + OFF_CEP;
    float* tr_part  = ws + OFF_TRP;

    hipLaunchKernelGGL(prep_kernel,  dim3(1280), dim3(256),  0, stream,
                       anchor, positive, negative, ex, la, Abf, Ebf, esq, asq, dref, tr_part, pmin);
    hipLaunchKernelGGL(main_kernel,  dim3(4096), dim3(256),  0, stream,
                       Abf, Ebf, asq, esq, outputs, la, ln, pmin, ce_part);
    hipLaunchKernelGGL(final_kernel, dim3(1),    dim3(1024), 0, stream,
                       ce_part, tr_part, pmin, dref, out);
}

// Round 5
// 42.624 us; speedup vs baseline: 1.1378x; 1.1112x over previous
//
#include <hip/hip_runtime.h>
#include <math.h>

// Problem constants
#define BB 4096      // batch
#define DD 512       // feature dim
#define CC 1000      // num classes

typedef __attribute__((ext_vector_type(8))) short short8;
typedef __attribute__((ext_vector_type(4))) float f32x4;

// ---------------- ws layout (float slots) ----------------
#define OFF_ABF  0              // 4096x512 bf16 = 1048576 float slots
#define OFF_EBF  1048576        // 1024x512 bf16 = 262144
#define OFF_ESQ  1310720        // 1024
#define OFF_ASQ  1311744        // 4096
#define OFF_DREF 1315840        // 4096
#define OFF_PMIN 1319936        // 4096
#define OFF_CEP  1324032        // 1536
#define OFF_TRP  1327104        // 1024

__device__ __forceinline__ unsigned short f2bf(float x) {
    unsigned u = __float_as_uint(x);
    unsigned r = (u + 0x7FFFu + ((u >> 16) & 1u)) >> 16;   // RNE
    return (unsigned short)r;
}

// ---------------------------------------------------------------------------
// prep: blocks [0,1024): triplet + asq + exact fp32 dref + anchor->bf16 + pmin=INF
//       blocks [1024,1280): exemplar->bf16 (padded) + esq
// ---------------------------------------------------------------------------
__global__ __launch_bounds__(256) void prep_kernel(
    const float* __restrict__ a, const float* __restrict__ p,
    const float* __restrict__ n, const float* __restrict__ ex,
    const int* __restrict__ la,
    unsigned short* __restrict__ Abf, unsigned short* __restrict__ Ebf,
    float* __restrict__ esq, float* __restrict__ asq,
    float* __restrict__ dref, float* __restrict__ tr_part,
    float* __restrict__ pmin)
{
    const int bid = blockIdx.x;
    const int wid = threadIdx.x >> 6, lane = threadIdx.x & 63;
    if (bid < 1024) {
        const int i = bid * 4 + wid;
        const int label = la[i];
        const float4* ar = (const float4*)(a + (size_t)i * DD);
        const float4* pr = (const float4*)(p + (size_t)i * DD);
        const float4* nr = (const float4*)(n + (size_t)i * DD);
        const float4* er = (const float4*)(ex + (size_t)label * DD);
        float sa = 0.f, sp = 0.f, sn = 0.f, se = 0.f;
#pragma unroll
        for (int k = 0; k < 2; k++) {
            const int j = lane + k * 64;
            float4 av = ar[j], pv = pr[j], nv = nr[j], ev = er[j];
            union { unsigned short u[4]; uint2 q; } o;
            o.u[0]=f2bf(av.x); o.u[1]=f2bf(av.y); o.u[2]=f2bf(av.z); o.u[3]=f2bf(av.w);
            *(uint2*)(Abf + (size_t)i * DD + j * 4) = o.q;
            sa += av.x*av.x + av.y*av.y + av.z*av.z + av.w*av.w;
            float dx = av.x-pv.x, dy = av.y-pv.y, dz = av.z-pv.z, dw = av.w-pv.w;
            sp += dx*dx + dy*dy + dz*dz + dw*dw;
            dx = av.x-nv.x; dy = av.y-nv.y; dz = av.z-nv.z; dw = av.w-nv.w;
            sn += dx*dx + dy*dy + dz*dz + dw*dw;
            dx = av.x-ev.x; dy = av.y-ev.y; dz = av.z-ev.z; dw = av.w-ev.w;
            se += dx*dx + dy*dy + dz*dz + dw*dw;
        }
        for (int off = 32; off; off >>= 1) {
            sa += __shfl_xor(sa, off);
            sp += __shfl_xor(sp, off);
            sn += __shfl_xor(sn, off);
            se += __shfl_xor(se, off);
        }
        __shared__ float ts[4];
        if (lane == 0) {
            asq[i]  = sa;
            dref[i] = sqrtf(se);
            pmin[i] = INFINITY;
            ts[wid] = fmaxf(sqrtf(sp) - sqrtf(sn), 0.f);
        }
        __syncthreads();
        if (threadIdx.x == 0) tr_part[bid] = ts[0] + ts[1] + ts[2] + ts[3];
    } else {
        const int c = (bid - 1024) * 4 + wid;   // [0,1024)
        float s = 0.f;
        if (c < CC) {
            const float4* row = (const float4*)(ex + (size_t)c * DD);
#pragma unroll
            for (int k = 0; k < 2; k++) {
                const int j = lane + k * 64;
                float4 v = row[j];
                union { unsigned short u[4]; uint2 q; } o;
                o.u[0]=f2bf(v.x); o.u[1]=f2bf(v.y); o.u[2]=f2bf(v.z); o.u[3]=f2bf(v.w);
                *(uint2*)(Ebf + (size_t)c * DD + j * 4) = o.q;
                s += v.x*v.x + v.y*v.y + v.z*v.z + v.w*v.w;
            }
            for (int off = 32; off; off >>= 1) s += __shfl_xor(s, off);
        } else {
            const uint2 z = make_uint2(0, 0);
#pragma unroll
            for (int k = 0; k < 2; k++) {
                const int j = lane + k * 64;
                *(uint2*)(Ebf + (size_t)c * DD + j * 4) = z;
            }
        }
        if (lane == 0) esq[c] = s;
    }
}

// ---------------------------------------------------------------------------
// main: 1664 blocks x 512 threads, XCD-uniform role chunks (208 chunks of 8).
//   chunk%13==0 -> GEMM (16 chunks = 128 blocks): 256x128 tile, BK=64
//   else        -> CE   (192 chunks = 1536 blocks): 8 rows/block
// ---------------------------------------------------------------------------
#define GL2LDS(gsrc, ldst) __builtin_amdgcn_global_load_lds( \
    (const __attribute__((address_space(1))) unsigned int*)(gsrc), \
    (__attribute__((address_space(3))) unsigned int*)(ldst), 16, 0, 0)

__global__ __launch_bounds__(512) void main_kernel(
    const unsigned short* __restrict__ Ab, const unsigned short* __restrict__ Eb,
    const float* __restrict__ asq, const float* __restrict__ esq,
    const float* __restrict__ outp,
    const int* __restrict__ la, const int* __restrict__ ln,
    float* __restrict__ pmin, float* __restrict__ ce_part)
{
    __shared__ unsigned short lA[256 * 64];     // 32 KB
    __shared__ unsigned short lB[128 * 64];     // 16 KB
    __shared__ float s_pm[2][256];              // 2 KB
    __shared__ float ps[8];

    const int bid = blockIdx.x;
    const int tid = threadIdx.x;
    const int w = tid >> 6, lane = tid & 63;
    const int chunk = bid >> 3, sub = bid & 7;

    if (chunk % 13 == 0) {
        // =================== GEMM 256x128 + fused distance/min ===================
        const int gb = (chunk / 13) * 8 + sub;          // [0,128)
        const int wm = w >> 1, wn = w & 1;              // 4x2 waves of 64x64 tiles
        const int hi = lane >> 4, lo = lane & 15;
        const int lrow = lane >> 3, l8 = lane & 7;
        const int gm0 = (gb >> 3) * 256, gn0 = (gb & 7) * 128;

        f32x4 acc[4][4];
#pragma unroll
        for (int mi = 0; mi < 4; mi++)
#pragma unroll
            for (int ni = 0; ni < 4; ni++) acc[mi][ni] = (f32x4){0.f, 0.f, 0.f, 0.f};

        for (int kt = 0; kt < DD / 64; kt++) {
            // ---- stage: wave w -> A rows [w*32, w*32+32), B rows [w*16, w*16+16)
#pragma unroll
            for (int i = 0; i < 4; i++) {
                int r0 = w * 32 + i * 8;
                int row = r0 + lrow;
                int c16 = l8 ^ (row & 7);
                GL2LDS(Ab + ((size_t)(gm0 + row) << 9) + kt * 64 + (c16 << 3), &lA[r0 * 64]);
            }
#pragma unroll
            for (int i = 0; i < 2; i++) {
                int r0 = w * 16 + i * 8;
                int row = r0 + lrow;
                int c16 = l8 ^ (row & 7);
                GL2LDS(Eb + ((size_t)(gn0 + row) << 9) + kt * 64 + (c16 << 3), &lB[r0 * 64]);
            }
            asm volatile("s_waitcnt vmcnt(0)" ::: "memory");
            __syncthreads();

            // ---- compute: 2 x K=32 substeps, 16 MFMA each ----
#pragma unroll
            for (int kk = 0; kk < 2; kk++) {
                int g16 = kk * 4 + hi;
                short8 af[4], bf[4];
#pragma unroll
                for (int mi = 0; mi < 4; mi++) {
                    int rA = wm * 64 + mi * 16 + lo;
                    af[mi] = *(const short8*)&lA[rA * 64 + ((g16 ^ (rA & 7)) << 3)];
                }
#pragma unroll
                for (int ni = 0; ni < 4; ni++) {
                    int rB = wn * 64 + ni * 16 + lo;
                    bf[ni] = *(const short8*)&lB[rB * 64 + ((g16 ^ (rB & 7)) << 3)];
                }
#pragma unroll
                for (int mi = 0; mi < 4; mi++)
#pragma unroll
                    for (int ni = 0; ni < 4; ni++)
                        acc[mi][ni] = __builtin_amdgcn_mfma_f32_16x16x32_bf16(af[mi], bf[ni], acc[mi][ni], 0, 0, 0);
            }
            __syncthreads();
        }

        // ---- epilogue: d = sqrt(asq + esq - 2 dot); row-min over 128 cols ----
        // C/D: col = lane&15, row = (lane>>4)*4 + j  [m89-verified]
        float aq[4][4];
#pragma unroll
        for (int mi = 0; mi < 4; mi++) {
            float4 a0 = *(const float4*)&asq[gm0 + wm * 64 + mi * 16 + hi * 4];
            aq[mi][0]=a0.x; aq[mi][1]=a0.y; aq[mi][2]=a0.z; aq[mi][3]=a0.w;
        }
        float esqc[4]; int bad[4];
#pragma unroll
        for (int ni = 0; ni < 4; ni++) {
            int gn = gn0 + wn * 64 + ni * 16 + lo;
            esqc[ni] = esq[gn];
            bad[ni] = (gn >= CC);
        }
        float vmin[4][4];
#pragma unroll
        for (int mi = 0; mi < 4; mi++)
#pragma unroll
            for (int j = 0; j < 4; j++) {
                float best = INFINITY;
#pragma unroll
                for (int ni = 0; ni < 4; ni++) {
                    float d2 = aq[mi][j] + esqc[ni] - 2.f * acc[mi][ni][j];
                    float d = sqrtf(fmaxf(d2, 0.f));
                    if (bad[ni]) d = INFINITY;
                    best = fminf(best, d);
                }
                vmin[mi][j] = best;
            }
#pragma unroll
        for (int off = 1; off < 16; off <<= 1)
#pragma unroll
            for (int mi = 0; mi < 4; mi++)
#pragma unroll
                for (int j = 0; j < 4; j++)
                    vmin[mi][j] = fminf(vmin[mi][j], __shfl_xor(vmin[mi][j], off));

        if (lo == 0) {
#pragma unroll
            for (int mi = 0; mi < 4; mi++)
#pragma unroll
                for (int j = 0; j < 4; j++)
                    s_pm[wn][wm * 64 + mi * 16 + hi * 4 + j] = vmin[mi][j];
        }
        __syncthreads();
        if (tid < 256) {
            float m2 = fminf(s_pm[0][tid], s_pm[1][tid]);
            // d >= 0 -> float order == int order; min is order-independent.
            atomicMin((int*)pmin + gm0 + tid, __float_as_int(m2));
        }
    } else {
        // =================== CE: one wave per row, float4 loads ===================
        const int cb = (chunk - chunk / 13 - 1) * 8 + sub;      // [0,1536)
        const int r = cb * 8 + w;                               // [0,12288)
        const int label = (r < 2 * BB) ? la[r & (BB - 1)] : ln[r - 2 * BB];
        const float4* row4 = (const float4*)(outp + (size_t)r * CC);   // 250 float4
        float4 v[4];
#pragma unroll
        for (int k = 0; k < 4; k++) {
            int j4 = lane + k * 64;
            v[k] = (j4 < 250) ? row4[j4]
                              : make_float4(-INFINITY, -INFINITY, -INFINITY, -INFINITY);
        }
        float m = -INFINITY;
#pragma unroll
        for (int k = 0; k < 4; k++)
            m = fmaxf(m, fmaxf(fmaxf(v[k].x, v[k].y), fmaxf(v[k].z, v[k].w)));
        for (int off = 32; off; off >>= 1) m = fmaxf(m, __shfl_xor(m, off));

        const int lj4 = label >> 2, lc = label & 3;
        float s = 0.f, lv = 0.f;
#pragma unroll
        for (int k = 0; k < 4; k++) {
            int j4 = lane + k * 64;
            s += __expf(v[k].x - m) + __expf(v[k].y - m)
               + __expf(v[k].z - m) + __expf(v[k].w - m);
            float comp = (lc == 0) ? v[k].x : (lc == 1) ? v[k].y : (lc == 2) ? v[k].z : v[k].w;
            lv += (j4 == lj4) ? comp : 0.f;
        }
        for (int off = 32; off; off >>= 1) {
            s += __shfl_xor(s, off);
            lv += __shfl_xor(lv, off);
        }
        if (lane == 0) ps[w] = -(lv - m - __logf(s));
        __syncthreads();
        if (tid == 0) {
            float t = 0.f;
#pragma unroll
            for (int q = 0; q < 8; q++) t += ps[q];
            ce_part[cb] = t;
        }
    }
}

// ---------------------------------------------------------------------------
// final: reduce partials; center loss from pmin + dref; combine.
// ---------------------------------------------------------------------------
__global__ __launch_bounds__(1024) void final_kernel(
    const float* __restrict__ ce_part, const float* __restrict__ tr_part,
    const float* __restrict__ pmin, const float* __restrict__ dref,
    float* __restrict__ out)
{
    int tid = threadIdx.x;
    float ce = 0.f, tr = tr_part[tid], ctr = 0.f;
    if (tid < 1536) ce = ce_part[tid] + ((tid < 512) ? ce_part[tid + 1024] : 0.f);
#pragma unroll
    for (int a = 0; a < 4; a++) {
        int m = a * 1024 + tid;
        ctr += fmaxf(dref[m] - pmin[m], 0.f);
    }
    for (int off = 32; off; off >>= 1) {
        ce += __shfl_xor(ce, off);
        tr += __shfl_xor(tr, off);
        ctr += __shfl_xor(ctr, off);
    }
    __shared__ float s[3][16];
    int wid = tid >> 6, lane = tid & 63;
    if (lane == 0) { s[0][wid] = ce; s[1][wid] = tr; s[2][wid] = ctr; }
    __syncthreads();
    if (tid == 0) {
        float tce = 0.f, ttr = 0.f, tctr = 0.f;
#pragma unroll
        for (int w = 0; w < 16; w++) { tce += s[0][w]; ttr += s[1][w]; tctr += s[2][w]; }
        float lsm = tce / (3.f * BB);
        out[0] = lsm + 0.1f * tctr + 1.0f * ttr;
        out[1] = ttr;
        out[2] = lsm;
        out[3] = tctr;
    }
}

extern "C" void kernel_launch(void* const* d_in, const int* in_sizes, int n_in,
                              void* d_out, int out_size, void* d_ws, size_t ws_size,
                              hipStream_t stream) {
    const float* anchor   = (const float*)d_in[0];
    const float* positive = (const float*)d_in[1];
    const float* negative = (const float*)d_in[2];
    const float* outputs  = (const float*)d_in[3];
    const int*   la       = (const int*)d_in[4];
    const int*   ln       = (const int*)d_in[5];
    const float* ex       = (const float*)d_in[6];
    float* out = (float*)d_out;
    float* ws  = (float*)d_ws;

    unsigned short* Abf = (unsigned short*)(ws + OFF_ABF);
    unsigned short* Ebf = (unsigned short*)(ws + OFF_EBF);
    float* esq      = ws + OFF_ESQ;
    float* asq      = ws + OFF_ASQ;
    float* dref     = ws + OFF_DREF;
    float* pmin     = ws + OFF_PMIN;
    float* ce_part  = ws + OFF_CEP;
    float* tr_part  = ws + OFF_TRP;

    hipLaunchKernelGGL(prep_kernel,  dim3(1280), dim3(256),  0, stream,
                       anchor, positive, negative, ex, la, Abf, Ebf, esq, asq, dref, tr_part, pmin);
    hipLaunchKernelGGL(main_kernel,  dim3(1664), dim3(512),  0, stream,
                       Abf, Ebf, asq, esq, outputs, la, ln, pmin, ce_part);
    hipLaunchKernelGGL(final_kernel, dim3(1),    dim3(1024), 0, stream,
                       ce_part, tr_part, pmin, dref, out);
}